// Round 5
// baseline (1282.556 us; speedup 1.0000x reference)
//
#include <hip/hip_runtime.h>
#include <hip/hip_bf16.h>

#define Bdim 64
#define Gdim 1024
#define Ddim 256
#define Fdim 1024

typedef short s8v __attribute__((ext_vector_type(8)));
typedef short s4v __attribute__((ext_vector_type(4)));
typedef float f4v __attribute__((ext_vector_type(4)));
typedef float f16f __attribute__((ext_vector_type(16)));

__device__ __forceinline__ float bf2f(short s){
  return __uint_as_float(((unsigned)(unsigned short)s) << 16);
}
__device__ __forceinline__ short f2bf(float f){
  unsigned u = __float_as_uint(f);
  u = u + 0x7fffu + ((u >> 16) & 1u);   // RNE
  return (short)(u >> 16);
}
__device__ __forceinline__ s8v ld8(const short* p){ return *(const s8v*)p; }

#define MFMA_BF16(a,b,c) __builtin_amdgcn_mfma_f32_16x16x32_bf16((a),(b),(c),0,0,0)
#define MFMA32(a,b,c)    __builtin_amdgcn_mfma_f32_32x32x16_bf16((a),(b),(c),0,0,0)

// async 16B global->LDS (linear dest; swizzle done on the SOURCE address)
#define GLDS16(gp, lp) __builtin_amdgcn_global_load_lds( \
    (const __attribute__((address_space(1))) void*)(gp), \
    (__attribute__((address_space(3))) void*)(lp), 16, 0, 0)

// ------------------------------------------------------------ dtype detection
__global__ __launch_bounds__(256) void detect_dtype(const unsigned* __restrict__ x,
                                                    int* __restrict__ flag){
  __shared__ int cnt[256];
  int c = 0;
  #pragma unroll
  for (int j=0;j<4;j++){
    unsigned u = x[threadIdx.x*4 + j];
    int e = (u >> 7) & 0xFF;
    c += (e >= 100 && e <= 140) ? 1 : 0;
  }
  cnt[threadIdx.x] = c;
  __syncthreads();
  if (threadIdx.x == 0){
    int s = 0;
    for (int i=0;i<256;i++) s += cnt[i];
    flag[0] = (s >= 512) ? 0 : 1;   // 0 = bf16 inputs, 1 = fp32 inputs
  }
}

// ------------------------------------------------------------ diagnostic
__global__ void diag_ws(void* o, float v, const int* __restrict__ flag){
  if (threadIdx.x == 0){
    if (flag[0]){ ((float*)o)[0] = v; ((float*)o)[16777216] = v; }
    else        { ((short*)o)[0] = f2bf(v); ((short*)o)[16777216] = f2bf(v); }
  }
}

// ------------------------------------------------------------ input -> fp32 h
__global__ __launch_bounds__(256) void cast_in(const void* __restrict__ x,
                                               float* __restrict__ h32,
                                               const int* __restrict__ flag){
  size_t i = ((size_t)blockIdx.x * 256 + threadIdx.x) * 8;
  if (flag[0]){
    const float* xf = (const float*)x;
    #pragma unroll
    for (int j=0;j<8;j++) h32[i+j] = xf[i+j];
  } else {
    s8v v = ld8((const short*)x + i);
    #pragma unroll
    for (int j=0;j<8;j++) h32[i+j] = bf2f(v[j]);
  }
}

// ------------------------------------------------------------ weight transpose -> bf16, stackable dst
__global__ __launch_bounds__(256) void transpose_w(const void* __restrict__ src,
                                                   short* __restrict__ dh, int R, int C,
                                                   const int* __restrict__ flag,
                                                   int dzs, int dbase){
  __shared__ short th[32][33];
  int fl = flag[0];
  size_t soff = (size_t)blockIdx.z * R * C;
  size_t doff = (size_t)dbase + (size_t)blockIdx.z * dzs;
  int c0 = blockIdx.x*32, r0 = blockIdx.y*32;
  int tx = threadIdx.x, ty = threadIdx.y;
  #pragma unroll
  for (int i=ty;i<32;i+=8){
    size_t idx = soff + (size_t)(r0+i)*C + (c0+tx);
    float w = fl ? ((const float*)src)[idx] : bf2f(((const short*)src)[idx]);
    th[i][tx] = f2bf(w);
  }
  __syncthreads();
  #pragma unroll
  for (int i=ty;i<32;i+=8)
    dh[doff + (size_t)(c0+i)*R + (r0+tx)] = th[tx][i];
}

// ------------------------------------------------------------ biases -> fp32
// [0..511]=bo(2x256)  [512..2559]=bf1(2x1024)  [2560..3071]=bf2(2x256)
__global__ __launch_bounds__(256) void bias_prep(const void* __restrict__ bo,
                                                 const void* __restrict__ bf1,
                                                 const void* __restrict__ bf2,
                                                 float* __restrict__ biasf,
                                                 const int* __restrict__ flag){
  int fl = flag[0];
  int i = blockIdx.x*256 + threadIdx.x;
  const void* src; int idx;
  if (i < 512){ src = bo; idx = i; }
  else if (i < 2560){ src = bf1; idx = i - 512; }
  else { src = bf2; idx = i - 2560; }
  biasf[i] = fl ? ((const float*)src)[idx] : bf2f(((const short*)src)[idx]);
}

// ------------------------------------------------------------ GEMM template
// AM: 0 = A bf16; 1 = A fp32 -> hi only; 2 = A fp32 -> hi+lo split (2 MFMA)
// EPI: 0 = bf16 store; 1 = relu(acc+bias) bf16 store;
//      4 = h32[idx] += acc + bias; 5 = fused QKV routing (Q,K row-major; V transposed)
template<int AM, int EPI>
__global__ __launch_bounds__(256) void gemm_t(
    const void* __restrict__ Ap, const short* __restrict__ Bh,
    const float* __restrict__ bias, float* __restrict__ hout,
    short* __restrict__ outb, int N, int K, int lda, int ldb, int Mrows)
{
  constexpr int AT = (AM==2) ? 2 : 1;
  __shared__ short As[AT*128*40];
  __shared__ short Bs[128*40];
  short* Asl = As + 128*40;
  const int tid = threadIdx.x;
  const int lane = tid & 63, wave = tid >> 6;
  const int quad = lane >> 4, l16 = lane & 15;
  const int m0 = blockIdx.x * 128, n0 = blockIdx.y * 128;
  const int wr = wave >> 1, wc = wave & 1;
  f4v acc[4][4];
  #pragma unroll
  for (int i=0;i<4;i++)
    #pragma unroll
    for (int j=0;j<4;j++) acc[i][j] = f4v{0.f,0.f,0.f,0.f};

  for (int k0 = 0; k0 < K; k0 += 32){
    __syncthreads();
    #pragma unroll
    for (int i=0;i<2;i++){
      int v = tid + i*256;
      int r = v >> 2, c8 = (v & 3) * 8;
      if (AM == 0){
        *(s8v*)(&As[r*40 + c8]) = ld8((const short*)Ap + (size_t)(m0 + r)*lda + k0 + c8);
      } else {
        const float* af = (const float*)Ap + (size_t)(m0 + r)*lda + k0 + c8;
        float4 f0 = *(const float4*)af;
        float4 f1 = *(const float4*)(af + 4);
        float fv[8] = {f0.x,f0.y,f0.z,f0.w,f1.x,f1.y,f1.z,f1.w};
        s8v hi, lo;
        #pragma unroll
        for (int j=0;j<8;j++) hi[j] = f2bf(fv[j]);
        *(s8v*)(&As[r*40 + c8]) = hi;
        if (AM == 2){
          #pragma unroll
          for (int j=0;j<8;j++) lo[j] = f2bf(fv[j] - bf2f(hi[j]));
          *(s8v*)(&Asl[r*40 + c8]) = lo;
        }
      }
      *(s8v*)(&Bs[r*40 + c8]) = ld8(Bh + (size_t)(n0 + r)*ldb + k0 + c8);
    }
    __syncthreads();
    s8v ah[4], al[4], bh[4];
    #pragma unroll
    for (int t=0;t<4;t++){
      ah[t] = ld8(&As[(wr*64 + t*16 + l16)*40 + quad*8]);
      bh[t] = ld8(&Bs[(wc*64 + t*16 + l16)*40 + quad*8]);
      if (AM == 2) al[t] = ld8(&Asl[(wr*64 + t*16 + l16)*40 + quad*8]);
    }
    #pragma unroll
    for (int ti=0;ti<4;ti++)
      #pragma unroll
      for (int tj=0;tj<4;tj++){
        acc[ti][tj] = MFMA_BF16(ah[ti], bh[tj], acc[ti][tj]);
        if (AM == 2) acc[ti][tj] = MFMA_BF16(al[ti], bh[tj], acc[ti][tj]);
      }
  }
  #pragma unroll
  for (int tj=0;tj<4;tj++){
    int col = n0 + wc*64 + tj*16 + l16;
    float bs = (EPI==1 || EPI==4) ? (bias ? bias[col] : 0.f) : 0.f;
    #pragma unroll
    for (int ti=0;ti<4;ti++){
      #pragma unroll
      for (int r=0;r<4;r++){
        int row = m0 + wr*64 + ti*16 + quad*4 + r;
        float v = acc[ti][tj][r];
        if (EPI == 0){
          outb[(size_t)row * N + col] = f2bf(v);
        } else if (EPI == 1){
          v += bs; v = v > 0.f ? v : 0.f;
          outb[(size_t)row * N + col] = f2bf(v);
        } else if (EPI == 4){
          size_t idx = (size_t)row * N + col;
          hout[idx] += v + bs;
        } else {  // EPI == 5: fused QKV
          int sec = col >> 8, c = col & 255;
          if (sec == 0)      outb[(size_t)row*256 + c] = f2bf(v);
          else if (sec == 1) (outb + (size_t)Mrows*256)[(size_t)row*256 + c] = f2bf(v);
          else {
            int bb = row >> 10, g = row & 1023;
            (outb + (size_t)2*Mrows*256)[(size_t)bb*262144 + (size_t)c*1024 + g] = f2bf(v);
          }
        }
      }
    }
  }
}

// ------------------------------------------------------------ flash attention v6
// 32x32x16 MFMA (2x FLOP per LDS byte vs 16x16x32). 8 waves x 32 q-rows with
// SPLIT-KV: waves 0-3 do keys [0,512), waves 4-7 do [512,1024) for the SAME
// 128 q-rows -> grid 8*CB = 1 block/CU, 8 waves/CU. KVBLK=32, two KV streams
// double-buffered in LDS (global_load_lds, src-XOR-swizzle). Q in registers
// (B-operand). Swapped QK^T: sc = MFMA32(K,Q) -> C[key][q], lane owns
// q=lane&31, 16 key-rows; softmax lane-local + 1 shfl_xor(32).
// P via per-wave LDS (stride 40 shorts: 16B-aligned b128, ~conflict-free).
// PV: A=P (2 frags, each reused 8x), B=V^T. Epilogue: flash-combine of the
// two KV halves through the (dead) K/V LDS.
__global__ __launch_bounds__(512, 2) void flash_attn(
    const short* __restrict__ Q, const short* __restrict__ Kmat,
    const short* __restrict__ Vt, const int* __restrict__ mask,
    short* __restrict__ H)
{
  __shared__ short Ks[2][2][8192];   // [stream][dbuf][32 keys * 256 d]  64 KiB
  __shared__ short Vs[2][2][8192];   // [stream][dbuf][256 d * 32 k]     64 KiB
  __shared__ short Ps[8][1280];      // [wave][32 q * 40]                20 KiB
  const int tid = threadIdx.x;
  const int lane = tid & 63, wave = tid >> 6;   // 8 waves
  const int hi = lane >> 5, l32 = lane & 31;
  const int g = wave & 3, kvh = wave >> 2;      // q-group, kv-half
  // batch -> XCD pinning: all 8 blocks of batch b share XCD b&7.
  const int bid = blockIdx.x;
  const int b  = (bid & 7) + ((bid >> 6) << 3);
  const int qt = (bid >> 3) & 7;
  const short* Qb  = Q    + (size_t)b*Gdim*Ddim;
  const short* Kb  = Kmat + (size_t)b*Gdim*Ddim;
  const short* Vtb = Vt   + (size_t)b*Ddim*Gdim;
  const int qbase = qt*128 + g*32;

  // per-thread staging chunk offsets (2 chunks per tile; 4 tiles per iter)
  int kco[2], vco[2], cdst[2];
  #pragma unroll
  for (int i=0;i<2;i++){
    int idx = i*512 + tid;
    int r = idx >> 5, gg = idx & 31;            // K: row=key(0..31), 16B slot
    kco[i] = r*256 + ((gg ^ (r & 7)) << 3);
    int d = idx >> 2, gv = idx & 3;             // V: row=d(0..255), 16B slot
    vco[i] = d*1024 + ((gv ^ (d & 3)) << 3);
    cdst[i] = idx*8;
  }
  auto stage = [&](int buf, int it){
    const short* k0p = Kb + (size_t)(it*32)*256;
    const short* k1p = k0p + 512*256;
    #pragma unroll
    for (int i=0;i<2;i++){
      GLDS16(k0p + kco[i], &Ks[0][buf][cdst[i]]);
      GLDS16(k1p + kco[i], &Ks[1][buf][cdst[i]]);
      GLDS16(Vtb + vco[i] + it*32,       &Vs[0][buf][cdst[i]]);
      GLDS16(Vtb + vco[i] + it*32 + 512, &Vs[1][buf][cdst[i]]);
    }
  };

  // Q B-fragments in registers: B[k][q]: q=lane&31, k=(lane>>5)*8+j per 16-slice
  s8v qf[16];
  const short* Qrow = Qb + (size_t)(qbase + l32)*Ddim + hi*8;
  #pragma unroll
  for (int s=0;s<16;s++) qf[s] = ld8(Qrow + s*16);
  float mrow = -1e9f, lsum = 0.f;    // per lane: q = l32 (this wave's kv half)
  f16f O[8];                          // O[dg]: d = dg*32+l32, q = crow(reg,hi)
  #pragma unroll
  for (int dg=0;dg<8;dg++)
    #pragma unroll
    for (int r=0;r<16;r++) O[dg][r] = 0.f;
  short* Pw = Ps[wave];

  stage(0, 0);
  __syncthreads();
  int cur = 0;
  const short* KsS = &Ks[kvh][0][0];
  const short* VsS = &Vs[kvh][0][0];
  const int mbase = b*Gdim + kvh*512;
  for (int it=0; it<16; it++){
    if (it < 15) stage(cur^1, it+1);
    int mv = mask[mbase + it*32 + l32];
    // ---- QK^T: C[key][q] = sum_d K[key][d] Q[q][d]; A=K from LDS, B=Q regs
    f16f sc;
    #pragma unroll
    for (int r=0;r<16;r++) sc[r] = 0.f;
    const short* Kst = KsS + cur*8192;
    const int krow = l32*256, ksw = l32 & 7;
    __builtin_amdgcn_s_setprio(1);
    #pragma unroll
    for (int s=0;s<16;s++){
      s8v kf = ld8(Kst + krow + (((s*2 + hi) ^ ksw) << 3));
      sc = MFMA32(kf, qf[s], sc);
    }
    __builtin_amdgcn_s_setprio(0);
    // ---- lane-local softmax: lane has 16 keys (rows) for query q=l32;
    //      partner lane^32 has the other 16. Masked -> -30, stays in
    //      denominator, zeroed in numerator.
    unsigned mb = (unsigned)__ballot(mv != 0);
    float pm = -1e9f;
    #pragma unroll
    for (int r=0;r<16;r++){
      int kk = (r & 3) + 8*(r >> 2) + 4*hi;
      float v = sc[r] * 0.0625f;
      if ((mb >> kk) & 1u) v = -30.f;
      sc[r] = v;
      pm = fmaxf(pm, v);
    }
    pm = fmaxf(pm, __shfl_xor(pm, 32));
    if (!__all(pm <= mrow + 8.f)){        // T13 defer-max, THR=8
      float mn = fmaxf(mrow, pm);
      float al = __expf(mrow - mn);
      mrow = mn; lsum *= al;
      #pragma unroll
      for (int r=0;r<16;r++){
        float alr = __shfl(al, (r & 3) + 8*(r >> 2) + 4*hi);
        #pragma unroll
        for (int dg=0;dg<8;dg++) O[dg][r] *= alr;
      }
    }
    float ps = 0.f;
    #pragma unroll
    for (int rq=0; rq<4; rq++){
      s4v pk;
      #pragma unroll
      for (int j=0;j<4;j++){
        int r = rq*4 + j;
        int kk = j + 8*rq + 4*hi;
        float e = __expf(sc[r] - mrow);
        ps += e;                                          // denominator keeps masked
        pk[j] = ((mb >> kk) & 1u) ? (short)0 : f2bf(e);   // numerator zeroed
      }
      *(s4v*)(&Pw[l32*40 + rq*8 + hi*4]) = pk;            // ds_write_b64
    }
    lsum += ps;
    asm volatile("s_waitcnt lgkmcnt(0)" ::: "memory");
    __builtin_amdgcn_sched_barrier(0);
    // ---- PV: O[q][d] += P[q][k] V[k][d]; A=P (2 frags, reused 8x), B=V^T
    const short* Vst = VsS + cur*8192;
    __builtin_amdgcn_s_setprio(1);
    #pragma unroll
    for (int c=0;c<2;c++){
      s8v pa = ld8(&Pw[l32*40 + c*16 + hi*8]);
      #pragma unroll
      for (int dg=0;dg<8;dg++){
        int d = dg*32 + l32;
        s8v vb = ld8(Vst + d*32 + ((((c*2 + hi) ^ (d & 3))) << 3));
        O[dg] = MFMA32(pa, vb, O[dg]);
      }
    }
    __builtin_amdgcn_s_setprio(0);
    __syncthreads();   // drains vmcnt (prefetch) + lgkm; buffer flip safe
    cur ^= 1;
  }
  // ---- merge the two KV halves (flash combine) through dead K/V LDS
  float dn = lsum + __shfl_xor(lsum, 32);   // full sum over this half's 512 keys
  float* scr = (g < 2) ? ((float*)&Ks[0][0][0] + g*8192)
                       : ((float*)&Vs[0][0][0] + (g - 2)*8192);
  float* ml = (float*)&Ps[0][0];
  if (kvh == 1){
    #pragma unroll
    for (int dg=0;dg<8;dg++)
      #pragma unroll
      for (int r=0;r<16;r++)
        scr[(dg*16 + r)*64 + lane] = O[dg][r];
    if (hi == 0){ ml[g*32 + l32] = mrow; ml[128 + g*32 + l32] = dn; }
  }
  __syncthreads();
  if (kvh == 0){
    float mh = ml[g*32 + l32], dh = ml[128 + g*32 + l32];
    float m12 = fmaxf(mrow, mh);
    float el = __expf(mrow - m12), eh = __expf(mh - m12);
    float dnf = dn*el + dh*eh;
    #pragma unroll
    for (int r=0;r<16;r++){
      int cr = (r & 3) + 8*(r >> 2) + 4*hi;
      float elr = __shfl(el, cr);
      float ehr = __shfl(eh, cr);
      float dnr = fmaxf(__shfl(dnf, cr), 1e-30f);
      int row = qbase + cr;
      #pragma unroll
      for (int dg=0;dg<8;dg++){
        float ov = O[dg][r]*elr + scr[(dg*16 + r)*64 + lane]*ehr;
        H[((size_t)b*Gdim + row)*Ddim + dg*32 + l32] = f2bf(ov / dnr);
      }
    }
  }
}

// ------------------------------------------------------------ mean + output
__global__ __launch_bounds__(256) void mean_partial(const float* __restrict__ h32,
                                                    float* __restrict__ part){
  int b = blockIdx.x, c = blockIdx.y, d = threadIdx.x;
  float s = 0.f;
  for (int g = c*64; g < c*64 + 64; g++)
    s += h32[((size_t)b*Gdim + g)*Ddim + d];
  part[(b*16 + c)*Ddim + d] = s;
}
__global__ __launch_bounds__(256) void mean_final_dyn(const float* __restrict__ part,
                                                      void* __restrict__ out,
                                                      const int* __restrict__ flag){
  int i = blockIdx.x*256 + threadIdx.x;
  int b = i >> 8, d = i & 255;
  float s = 0.f;
  #pragma unroll
  for (int c=0;c<16;c++) s += part[(b*16 + c)*Ddim + d];
  s *= (1.f/1024.f);
  if (flag[0]) ((float*)out)[16777216 + i] = s;
  else         ((short*)out)[16777216 + i] = f2bf(s);
}
__global__ __launch_bounds__(256) void store_h(const float* __restrict__ h32,
                                               void* __restrict__ out,
                                               const int* __restrict__ flag){
  size_t i = (size_t)blockIdx.x*256 + threadIdx.x;
  if (flag[0]) ((float*)out)[i] = h32[i];
  else         ((short*)out)[i] = f2bf(h32[i]);
}

// ------------------------------------------------------------ launch
extern "C" void kernel_launch(void* const* d_in, const int* in_sizes, int n_in,
                              void* d_out, int out_size, void* d_ws, size_t ws_size,
                              hipStream_t stream)
{
  const void* xs  = d_in[0];
  const int*  mask= (const int*)d_in[1];
  const void* Wq  = d_in[2];
  const void* Wk  = d_in[3];
  const void* Wv  = d_in[4];
  const void* Wo  = d_in[5];
  const void* bo  = d_in[6];
  const void* Wf1 = d_in[7];
  const void* bf1 = d_in[8];
  const void* Wf2 = d_in[9];
  const void* bf2 = d_in[10];

  // weights: Wqkv(768K) + Wo(256K) + Wf1(1M) + Wf2(1M) + biasf(12K)
  const size_t W_ALL = 786432 + 262144 + 1048576 + 1048576 + 12288;  // 3,158,016
  const size_t BASE  = 256 + 67108864;                               // flag + h32
  int CB;
  if      (ws_size >= BASE + 134217728ull + W_ALL) CB = 64;   // 204.5 MB
  else if (ws_size >= BASE +  67108864ull + W_ALL) CB = 32;   // 137.4 MB (proven reachable)
  else if (ws_size >= BASE +  33554432ull + W_ALL) CB = 16;
  else CB = 0;

  char* p = (char*)d_ws;
  int* flag = (int*)p; p += 256;
  detect_dtype<<<1, 256, 0, stream>>>((const unsigned*)xs, flag);
  if (CB == 0){
    diag_ws<<<1, 64, 0, stream>>>(d_out, 2000.f + (float)(ws_size >> 20), flag);
    return;
  }
  const int M = CB * 1024, nch = 64 / CB;
  float* h32 = (float*)p; p += 67108864;
  char* arena = p;        p += (size_t)CB * 2097152;
  short* WqkvT = (short*)p; p += 786432;
  short* WoT   = (short*)p; p += 262144;
  short* Wf1T  = (short*)p; p += 1048576;
  short* Wf2T  = (short*)p; p += 1048576;
  float* biasf = (float*)p; p += 12288;
  float* part  = (float*)arena;          // arena dead by mean time

  short* Qc  = (short*)arena;
  short* Kc  = Qc + (size_t)M*256;
  short* Vtc = Qc + (size_t)2*M*256;
  short* Hc  = Qc + (size_t)3*M*256;
  short* Tc  = Qc;                       // FFN intermediate spans whole arena

  cast_in<<<8192, 256, 0, stream>>>(xs, h32, flag);
  dim3 tb(32,8);
  transpose_w<<<dim3(8,8,2),  tb, 0, stream>>>(Wq,  WqkvT, 256, 256,  flag, 196608, 0);
  transpose_w<<<dim3(8,8,2),  tb, 0, stream>>>(Wk,  WqkvT, 256, 256,  flag, 196608, 65536);
  transpose_w<<<dim3(8,8,2),  tb, 0, stream>>>(Wv,  WqkvT, 256, 256,  flag, 196608, 131072);
  transpose_w<<<dim3(8,8,2),  tb, 0, stream>>>(Wo,  WoT,   256, 256,  flag, 65536, 0);
  transpose_w<<<dim3(32,8,2), tb, 0, stream>>>(Wf1, Wf1T,  256, 1024, flag, 262144, 0);
  transpose_w<<<dim3(8,32,2), tb, 0, stream>>>(Wf2, Wf2T,  1024, 256, flag, 262144, 0);
  bias_prep<<<12, 256, 0, stream>>>(bo, bf1, bf2, biasf, flag);

  for (int c=0; c<nch; c++){
    float* hc = h32 + (size_t)c*M*256;
    const int* mc = mask + (size_t)c*M;
    for (int l=0; l<2; l++){
      // fused QKV: A = h fp32 (hi), B = stacked [768][256]
      gemm_t<1,5><<<dim3(M/128,6), 256, 0, stream>>>(hc, WqkvT + l*196608, nullptr,
                                                     nullptr, Qc, 768, 256, 256, 256, M);
      flash_attn<<<dim3(8*CB), 512, 0, stream>>>(Qc, Kc, Vtc, mc, Hc);
      // O-proj: h32 += Hc*Wo + bo
      gemm_t<0,4><<<dim3(M/128,2), 256, 0, stream>>>(Hc, WoT + l*65536, biasf + l*256,
                                                     hc, nullptr, 256, 256, 256, 256, M);
      // FFN1: T = relu(h*Wf1 + b), A split
      gemm_t<2,1><<<dim3(M/128,8), 256, 0, stream>>>(hc, Wf1T + l*262144, biasf + 512 + l*1024,
                                                     nullptr, Tc, 1024, 256, 256, 256, M);
      // FFN2: h32 += T*Wf2 + b
      gemm_t<0,4><<<dim3(M/128,2), 256, 0, stream>>>(Tc, Wf2T + l*262144, biasf + 2560 + l*256,
                                                     hc, nullptr, 256, 1024, 1024, 1024, M);
    }
  }
  mean_partial<<<dim3(64,16), 256, 0, stream>>>(h32, part);
  store_h<<<65536, 256, 0, stream>>>(h32, d_out, flag);
  mean_final_dyn<<<64, 256, 0, stream>>>(part, d_out, flag);
}